// Round 6
// baseline (110.985 us; speedup 1.0000x reference)
//
#include <hip/hip_runtime.h>
#include <stdint.h>

// GateDotProductAttention: B=8,S=2048,D=256 fp32 in/out.
// prep: K -> bf16 swizzled LDS-image tiles, V -> V^T bf16 80B-stride tiles, W -> bf16 chunks (d_ws)
// attn: fused bidirectional flash attention, no-max softmax, j-split across wave halves,
//       swapped QK^T (scores transposed) -> in-register softmax -> PV via 16x16x16 MFMA
//       (P never touches LDS), fused gate GEMMs + sigmoid blend. Single out write.

typedef unsigned short u16;
typedef unsigned int u32;
typedef __attribute__((ext_vector_type(8))) short short8;
typedef __attribute__((ext_vector_type(4))) short short4v;
typedef __attribute__((ext_vector_type(4))) float f32x4;

#define B_ 8
#define S_ 2048
#define D_ 256
#define QB 64
#define NP 32            // periods, 64 j-rows each

#define LOG2E 1.44269504088896340736f
#define QSCALE (LOG2E/16.0f)   // fold 1/sqrt(256) and log2(e) into Q

#define KSWZ_OFF 0
#define VT_OFF   (8u<<20)
#define VT_PERIOD 40960u               // 2 x (256 rows x 80B)
#define VT_BATCH (32u*VT_PERIOD)
#define WBF_OFF  (VT_OFF + 8u*VT_BATCH)

// LDS map (attn): K dbuf [0,64K) ; V dbuf [64K,64K+80K=147456)
#define LDS_K  0
#define LDS_V  65536
#define LDS_SUM 131072   // epilogue sums (written P0, read P1; no overlap with W bufs)
// epilogue reuse: merge-F @0, merge-B @65536, att image @ h*32768, W @65536+buf*32768

__device__ __forceinline__ u16 f2bf(float f) {
    union { float f; u32 u; } x; x.f = f;
    u32 u = x.u + 0x7fffu + ((x.u >> 16) & 1u);   // RNE
    return (u16)(u >> 16);
}
__device__ __forceinline__ short8 pack8(float4 a, float4 b) {
    short8 r;
    r[0] = (short)f2bf(a.x); r[1] = (short)f2bf(a.y);
    r[2] = (short)f2bf(a.z); r[3] = (short)f2bf(a.w);
    r[4] = (short)f2bf(b.x); r[5] = (short)f2bf(b.y);
    r[6] = (short)f2bf(b.z); r[7] = (short)f2bf(b.w);
    return r;
}
__device__ __forceinline__ f32x4 mfma16(short8 a, short8 b, f32x4 c) {
    return __builtin_amdgcn_mfma_f32_16x16x32_bf16(a, b, c, 0, 0, 0);
}
__device__ __forceinline__ f32x4 mfma161(short4v a, short4v b, f32x4 c) {
#if __has_builtin(__builtin_amdgcn_mfma_f32_16x16x16bf16_1k)
    return __builtin_amdgcn_mfma_f32_16x16x16bf16_1k(a, b, c, 0, 0, 0);
#elif __has_builtin(__builtin_amdgcn_mfma_f32_16x16x16_bf16)
    return __builtin_amdgcn_mfma_f32_16x16x16_bf16(a, b, c, 0, 0, 0);
#else
    f32x4 d;
    asm volatile("v_mfma_f32_16x16x16_bf16 %0, %1, %2, %3"
                 : "=v"(d) : "v"(a), "v"(b), "v"(c));
    return d;
#endif
}
// pack 4 f32 -> 4 bf16 (RNE) in-lane; v_cvt_pk_bf16_f32 has no builtin on gfx950
__device__ __forceinline__ short4v pkbf(float a0, float a1, float a2, float a3) {
    union { u32 w[2]; short4v v; } u;
    asm("v_cvt_pk_bf16_f32 %0, %1, %2" : "=v"(u.w[0]) : "v"(a0), "v"(a1));
    asm("v_cvt_pk_bf16_f32 %0, %1, %2" : "=v"(u.w[1]) : "v"(a2), "v"(a3));
    return u.v;
}
__device__ __forceinline__ void gload_lds(const void* g, void* lds) {
    __builtin_amdgcn_global_load_lds(
        (const __attribute__((address_space(1))) void*)g,
        (__attribute__((address_space(3))) void*)lds, 16, 0, 0);
}

// ---------------------------------------------------------------- prep ----
__global__ __launch_bounds__(256, 1)
void prep_kernel(const float* __restrict__ k, const float* __restrict__ v,
                 const float* __restrict__ w0, const float* __restrict__ w1,
                 const float* __restrict__ w2, const float* __restrict__ w3,
                 char* __restrict__ ws)
{
    const int tid = (int)threadIdx.x;
    const int bid = (int)blockIdx.x;

    if (bid < 512) {
        // ---- V transpose tile: (b, jt) -> V^T [256 d][32 j] bf16, 80B row stride
        __shared__ float vs[32][257];
        const int b = bid >> 6, jt = bid & 63;
        const float* vb = v + ((size_t)b * S_ + (size_t)jt * 32) * D_;
        const int j = tid >> 3, d0 = (tid & 7) * 32;
        #pragma unroll
        for (int i = 0; i < 8; ++i) {
            float4 x = *(const float4*)(vb + (size_t)j * D_ + d0 + i * 4);
            vs[j][d0 + i * 4 + 0] = x.x; vs[j][d0 + i * 4 + 1] = x.y;
            vs[j][d0 + i * 4 + 2] = x.z; vs[j][d0 + i * 4 + 3] = x.w;
        }
        __syncthreads();
        char* ob = ws + VT_OFF + (size_t)b * VT_BATCH + (size_t)(jt >> 1) * VT_PERIOD
                   + (size_t)(jt & 1) * 20480 + (size_t)tid * 80;
        short8 o[4];
        #pragma unroll
        for (int jj = 0; jj < 32; ++jj) o[jj >> 3][jj & 7] = (short)f2bf(vs[jj][tid]);
        #pragma unroll
        for (int i = 0; i < 4; ++i) *(short8*)(ob + i * 16) = o[i];
    } else if (bid < 1024) {
        // ---- K tile -> swizzled bf16 LDS image: row r, byte = r*512 + ((cg*16) ^ ((r&7)<<4))
        const int t = bid - 512, b = t >> 6, jt = t & 63;
        const float* kb = k + ((size_t)b * S_ + (size_t)jt * 32) * D_;
        char* ob = ws + KSWZ_OFF + (size_t)(b * 64 + jt) * 16384;
        #pragma unroll
        for (int it = 0; it < 4; ++it) {
            int gi = tid + it * 256;
            int r = gi >> 5, cg = gi & 31;
            float4 x0 = *(const float4*)(kb + (size_t)r * D_ + cg * 8);
            float4 x1 = *(const float4*)(kb + (size_t)r * D_ + cg * 8 + 4);
            *(short8*)(ob + r * 512 + ((cg * 16) ^ ((r & 7) << 4))) = pack8(x0, x1);
        }
    } else {
        // ---- W slice (m, db): 16 rows x 256 cols -> swizzled bf16, chunk order (db*4+m)
        const int t = bid - 1024, m = t >> 4, db = t & 15;
        const float* wsrc = (m == 0 ? w0 : m == 1 ? w1 : m == 2 ? w2 : w3)
                            + (size_t)(db * 16) * D_;
        char* ob = ws + WBF_OFF + (size_t)(db * 4 + m) * 8192;
        #pragma unroll
        for (int it = 0; it < 2; ++it) {
            int gi = tid + it * 256;
            int r = gi >> 5, cg = gi & 31;
            float4 x0 = *(const float4*)(wsrc + (size_t)r * D_ + cg * 8);
            float4 x1 = *(const float4*)(wsrc + (size_t)r * D_ + cg * 8 + 4);
            *(short8*)(ob + r * 512 + ((cg * 16) ^ ((r & 7) << 4))) = pack8(x0, x1);
        }
    }
}

// ---------------------------------------------------------------- attn ----
// PV from in-register P A-frags (16x16x16): B-frags = two b64 reads per d-block from V^T.
#define PV_REG(paL_, paH_, accD, accS)                                         \
    {                                                                          \
        __builtin_amdgcn_s_setprio(1);                                         \
        accS = mfma161(paL_, onesb4, accS);                                    \
        accS = mfma161(paH_, onesb4, accS);                                    \
        _Pragma("unroll")                                                      \
        for (int db = 0; db < 16; ++db) {                                      \
            const char* vp_ = vcur + (db * 16 + c) * 80 + g * 8;               \
            short4v vlo = *(const short4v*)(vp_);                              \
            short4v vhi = *(const short4v*)(vp_ + 32);                         \
            accD[db] = mfma161(paL_, vlo, accD[db]);                           \
            accD[db] = mfma161(paH_, vhi, accD[db]);                           \
        }                                                                      \
        __builtin_amdgcn_s_setprio(0);                                         \
    }

__global__ __launch_bounds__(512, 2)
void attn_kernel(const float* __restrict__ q, const char* __restrict__ kswz,
                 const char* __restrict__ vt, const char* __restrict__ wbf,
                 const float* __restrict__ v,
                 const float* __restrict__ bo0, const float* __restrict__ bo1,
                 float* __restrict__ out)
{
    __shared__ char smem[147456];

    const int tid = (int)threadIdx.x;
    const int wv = tid >> 6, lane = tid & 63;
    const int h = wv >> 2, wl = wv & 3;
    const int g = lane >> 4, c = lane & 15;
    const int bid = (int)blockIdx.x;
    const int b = bid & 7, qi = bid >> 3;
    const int q0 = qi * QB;
    const int r0 = q0 + wl * 16;            // global q row base of this wave
    const int dt = r0 >> 5;                 // diagonal 32-j-block index

    const char* kbaseg = kswz + (size_t)b * (64 * 16384);
    const char* vbaseg = vt + (size_t)b * VT_BATCH;

    // Q frags (pre-scaled). Used as the MFMA *B* operand in swapped QK^T.
    short8 qf[8];
    {
        const float* qp = q + ((size_t)b * S_ + (size_t)(r0 + c)) * D_;
        #pragma unroll
        for (int ks = 0; ks < 8; ++ks) {
            float4 a = *(const float4*)(qp + ks * 32 + g * 8);
            float4 d = *(const float4*)(qp + ks * 32 + g * 8 + 4);
            a.x *= QSCALE; a.y *= QSCALE; a.z *= QSCALE; a.w *= QSCALE;
            d.x *= QSCALE; d.y *= QSCALE; d.z *= QSCALE; d.w *= QSCALE;
            qf[ks] = pack8(a, d);
        }
    }

    short4v onesb4;
    #pragma unroll
    for (int i = 0; i < 4; ++i) onesb4[i] = (c == 0) ? (short)0x3F80 : (short)0;

    const f32x4 zero4 = {0.f, 0.f, 0.f, 0.f};
    f32x4 accF[16], accB[16], accSF = zero4, accSB = zero4;
    #pragma unroll
    for (int i = 0; i < 16; ++i) { accF[i] = zero4; accB[i] = zero4; }

    // stage one 64-row period: 32KB K (4 rounds) + 40KB V^T (5 rounds)
    #define STAGE(t, buf)                                                      \
        {                                                                      \
            const char* kg_ = kbaseg + (size_t)(t) * 32768;                    \
            const char* vg_ = vbaseg + (size_t)(t) * VT_PERIOD;                \
            _Pragma("unroll")                                                  \
            for (int i = 0; i < 4; ++i) {                                      \
                int off = i * 8192 + wv * 1024;                                \
                gload_lds(kg_ + off + lane * 16, smem + LDS_K + (buf) * 32768 + off); \
            }                                                                  \
            _Pragma("unroll")                                                  \
            for (int i = 0; i < 5; ++i) {                                      \
                int off = i * 8192 + wv * 1024;                                \
                gload_lds(vg_ + off + lane * 16, smem + LDS_V + (buf) * 40960 + off); \
            }                                                                  \
        }

    STAGE(0, 0);
    __syncthreads();

    const int swz = (c & 7) << 4;

    #pragma unroll 1
    for (int t = 0; t < NP; ++t) {
        const int cur = t & 1;
        if (t + 1 < NP) STAGE(t + 1, cur ^ 1);

        const int jw = 2 * t + h;           // this wave's 32-j block index
        const int j0 = jw * 32;
        const char* kcur = smem + LDS_K + cur * 32768 + h * 16384;
        const char* vcur = smem + LDS_V + cur * 40960 + h * 20480;

        // ---- swapped QK^T: scT[j][q]  (K rows as A, Q as B)
        f32x4 scT0 = zero4, scT1 = zero4;
        __builtin_amdgcn_s_setprio(1);
        #pragma unroll
        for (int ks = 0; ks < 8; ++ks) {
            int inner = (ks * 64 + g * 16) ^ swz;
            short8 kb0 = *(const short8*)(kcur + c * 512 + inner);
            short8 kb1 = *(const short8*)(kcur + (16 + c) * 512 + inner);
            scT0 = mfma16(kb0, qf[ks], scT0);
            scT1 = mfma16(kb1, qf[ks], scT1);
        }
        __builtin_amdgcn_s_setprio(0);

        // ---- softmax numerator in registers; P stays in VGPRs as 16x16x16 A-frags.
        // lane holds scT*[j = 4g + r][q = c]  (j relative to tile base)
        if (jw != dt) {
            short4v paL = pkbf(exp2f(scT0[0]), exp2f(scT0[1]), exp2f(scT0[2]), exp2f(scT0[3]));
            short4v paH = pkbf(exp2f(scT1[0]), exp2f(scT1[1]), exp2f(scT1[2]), exp2f(scT1[3]));
            if (jw < dt) {
                PV_REG(paL, paH, accB, accSB);
            } else {
                PV_REG(paL, paH, accF, accSF);
            }
        } else {
            const int qq = r0 + c;
            float m0[4], m1[4], n0[4], n1[4];
            #pragma unroll
            for (int r = 0; r < 4; ++r) {
                int jgl = j0 + 4 * g + r;
                int jgh = j0 + 16 + 4 * g + r;
                float v0 = exp2f(scT0[r]), v1 = exp2f(scT1[r]);
                m0[r] = (jgl <= qq) ? v0 : 0.0f;   // bw: j <= q
                m1[r] = (jgh <= qq) ? v1 : 0.0f;
                n0[r] = (jgl >= qq) ? v0 : 0.0f;   // fw: j >= q
                n1[r] = (jgh >= qq) ? v1 : 0.0f;
            }
            short4v pbL = pkbf(m0[0], m0[1], m0[2], m0[3]);
            short4v pbH = pkbf(m1[0], m1[1], m1[2], m1[3]);
            short4v pfL = pkbf(n0[0], n0[1], n0[2], n0[3]);
            short4v pfH = pkbf(n1[0], n1[1], n1[2], n1[3]);
            PV_REG(pbL, pbH, accB, accSB);
            PV_REG(pfL, pfH, accF, accSF);
        }
        __syncthreads();
    }

    // ---- epilogue: merge halves, then fused gate ----
    float* sumsA = (float*)(smem + LDS_SUM);        // sF partial from half1 (64)
    float* sumsB = (float*)(smem + LDS_SUM + 256);  // sB partial from half0 (64)

    // P0: exchange partials (half1 acc-F -> [0,64K), half0 acc-B -> [64K,128K))
    if (h == 1) {
        float* dst = (float*)smem + wl * 4096;
        #pragma unroll
        for (int db = 0; db < 16; ++db)
            #pragma unroll
            for (int r = 0; r < 4; ++r)
                dst[(g * 4 + r) * 256 + db * 16 + c] = accF[db][r];
        if (c == 0) {
            #pragma unroll
            for (int r = 0; r < 4; ++r) sumsA[wl * 16 + g * 4 + r] = accSF[r];
        }
    } else {
        float* dst = (float*)(smem + LDS_V) + wl * 4096;
        #pragma unroll
        for (int db = 0; db < 16; ++db)
            #pragma unroll
            for (int r = 0; r < 4; ++r)
                dst[(g * 4 + r) * 256 + db * 16 + c] = accB[db][r];
        if (c == 0) {
            #pragma unroll
            for (int r = 0; r < 4; ++r) sumsB[wl * 16 + g * 4 + r] = accSB[r];
        }
    }
    __syncthreads();

    // P1: merge + normalize. half0 owns fw rows, half1 owns bw rows.
    f32x4 merged[16];
    if (h == 0) {
        const float* src = (const float*)smem + wl * 4096;
        float rs[4];
        #pragma unroll
        for (int r = 0; r < 4; ++r) {
            float so = __shfl(accSF[r], lane & 48);
            rs[r] = 1.0f / (so + sumsA[wl * 16 + g * 4 + r]);
        }
        #pragma unroll
        for (int db = 0; db < 16; ++db)
            #pragma unroll
            for (int r = 0; r < 4; ++r)
                merged[db][r] = (accF[db][r] + src[(g * 4 + r) * 256 + db * 16 + c]) * rs[r];
    } else {
        const float* src = (const float*)(smem + LDS_V) + wl * 4096;
        float rs[4];
        #pragma unroll
        for (int r = 0; r < 4; ++r) {
            float so = __shfl(accSB[r], lane & 48);
            rs[r] = 1.0f / (so + sumsB[wl * 16 + g * 4 + r]);
        }
        #pragma unroll
        for (int db = 0; db < 16; ++db)
            #pragma unroll
            for (int r = 0; r < 4; ++r)
                merged[db][r] = (accB[db][r] + src[(g * 4 + r) * 256 + db * 16 + c]) * rs[r];
    }
    __syncthreads();

    // P2: write att_v bf16 swizzled image (h0: fw @[0,32K), h1: bw @[32K,64K)) + stage W chunk 0
    {
        char* imgb = smem + h * 32768;
        #pragma unroll
        for (int db = 0; db < 16; ++db)
            #pragma unroll
            for (int r = 0; r < 4; ++r) {
                int lr = wl * 16 + g * 4 + r;
                int cb = (db * 16 + c) * 2;
                *(u16*)(imgb + lr * 512 + (cb ^ ((lr & 7) << 4))) = f2bf(merged[db][r]);
            }
    }
    #define WSTAGE(db, buf)                                                    \
        {                                                                      \
            const char* gsrc = wbf + (size_t)(db) * 32768;                     \
            _Pragma("unroll")                                                  \
            for (int i = 0; i < 4; ++i) {                                      \
                int off = i * 8192 + wv * 1024;                                \
                gload_lds(gsrc + off + lane * 16,                              \
                          smem + LDS_V + (buf) * 32768 + off);                 \
            }                                                                  \
        }
    WSTAGE(0, 0);
    __syncthreads();

    // P3: A-frags for own direction (att image) and v (global)
    short8 af[8], vf[8];
    {
        const char* imgb = smem + h * 32768;
        int lr = wl * 16 + c;
        #pragma unroll
        for (int ks = 0; ks < 8; ++ks) {
            int inner = (ks * 64 + g * 16) ^ swz;
            af[ks] = *(const short8*)(imgb + lr * 512 + inner);
        }
        const float* vp = v + ((size_t)b * S_ + (size_t)(r0 + c)) * D_;
        #pragma unroll
        for (int ks = 0; ks < 8; ++ks) {
            float4 a = *(const float4*)(vp + ks * 32 + g * 8);
            float4 d = *(const float4*)(vp + ks * 32 + g * 8 + 4);
            vf[ks] = pack8(a, d);
        }
    }

    // db loop: gate GEMM (own direction) + blend + store
    const float* bias = (h == 0) ? bo0 : bo1;
    const float* vrow = v + ((size_t)b * S_ + (size_t)r0) * D_;
    float* ob = out + ((size_t)b * S_ + (size_t)r0) * 512 + h * 256;
    #pragma unroll
    for (int db = 0; db < 16; ++db) {
        const int cu2 = db & 1;
        if (db + 1 < 16) WSTAGE(db + 1, cu2 ^ 1);

        float bb = bias[db * 16 + c];
        f32x4 a = {bb, bb, bb, bb};
        const char* wc = smem + LDS_V + cu2 * 32768 + h * 16384;
        __builtin_amdgcn_s_setprio(1);
        #pragma unroll
        for (int ks = 0; ks < 8; ++ks) {
            int inner = (ks * 64 + g * 16) ^ swz;
            short8 wi = *(const short8*)(wc + c * 512 + inner);
            short8 wo = *(const short8*)(wc + 8192 + c * 512 + inner);
            a = mfma16(vf[ks], wi, a);
            a = mfma16(af[ks], wo, a);
        }
        __builtin_amdgcn_s_setprio(0);

        #pragma unroll
        for (int r = 0; r < 4; ++r) {
            int row = g * 4 + r;
            float vv = vrow[(size_t)row * D_ + db * 16 + c];
            float gate = 1.0f / (1.0f + exp2f(-a[r] * LOG2E));
            float m = merged[db][r];
            ob[(size_t)row * 512 + db * 16 + c] = gate * m + (1.0f - gate) * vv;
        }
        __syncthreads();
    }
}

extern "C" void kernel_launch(void* const* d_in, const int* in_sizes, int n_in,
                              void* d_out, int out_size, void* d_ws, size_t ws_size,
                              hipStream_t stream)
{
    const float* q   = (const float*)d_in[0];
    const float* k   = (const float*)d_in[1];
    const float* v   = (const float*)d_in[2];
    const float* Wi0 = (const float*)d_in[3];
    const float* Wi1 = (const float*)d_in[4];
    const float* Wo0 = (const float*)d_in[5];
    const float* Wo1 = (const float*)d_in[6];
    const float* bo0 = (const float*)d_in[7];
    const float* bo1 = (const float*)d_in[8];
    float* out = (float*)d_out;
    char* ws = (char*)d_ws;
    (void)in_sizes; (void)n_in; (void)ws_size; (void)out_size;

    // prep: K-swz [0,8MB), V^T 80B-stride [8MB,18MB), W-bf16 chunks [18MB,+512KB)
    prep_kernel<<<dim3(1088), dim3(256), 0, stream>>>(k, v, Wi0, Wo0, Wi1, Wo1, ws);
    attn_kernel<<<dim3(256), dim3(512), 0, stream>>>(q, ws + KSWZ_OFF, ws + VT_OFF,
                                                     ws + WBF_OFF, v, bo0, bo1, out);
}

// Round 7
// 103.269 us; speedup vs baseline: 1.0747x; 1.0747x over previous
//
#include <hip/hip_runtime.h>
#include <stdint.h>

// GateDotProductAttention: B=8,S=2048,D=256 fp32 in/out.
// prep: K -> bf16 swizzled LDS-image tiles, V -> V^T bf16 80B-stride tiles, W -> bf16 chunks (d_ws)
// attn: fused bidirectional flash attention, no-max softmax, j-split across wave halves,
//       swapped QK^T -> in-register softmax -> ds_bpermute repack to 16x16x32 A-frags -> PV
//       (P never touches LDS; PV at full-K MFMA rate), fused gate GEMMs + blend.

typedef unsigned short u16;
typedef unsigned int u32;
typedef __attribute__((ext_vector_type(8))) short short8;
typedef __attribute__((ext_vector_type(4))) float f32x4;

#define B_ 8
#define S_ 2048
#define D_ 256
#define QB 64
#define NP 32            // periods, 64 j-rows each

#define LOG2E 1.44269504088896340736f
#define QSCALE (LOG2E/16.0f)   // fold 1/sqrt(256) and log2(e) into Q

#define KSWZ_OFF 0
#define VT_OFF   (8u<<20)
#define VT_PERIOD 40960u               // 2 x (256 rows x 80B)
#define VT_BATCH (32u*VT_PERIOD)
#define WBF_OFF  (VT_OFF + 8u*VT_BATCH)

// LDS map (attn): K dbuf [0,64K) ; V dbuf [64K,64K+80K=147456)
#define LDS_K  0
#define LDS_V  65536
#define LDS_SUM 131072   // epilogue sums (W bufs end exactly here)

__device__ __forceinline__ u16 f2bf(float f) {
    union { float f; u32 u; } x; x.f = f;
    u32 u = x.u + 0x7fffu + ((x.u >> 16) & 1u);   // RNE
    return (u16)(u >> 16);
}
__device__ __forceinline__ short8 pack8(float4 a, float4 b) {
    short8 r;
    r[0] = (short)f2bf(a.x); r[1] = (short)f2bf(a.y);
    r[2] = (short)f2bf(a.z); r[3] = (short)f2bf(a.w);
    r[4] = (short)f2bf(b.x); r[5] = (short)f2bf(b.y);
    r[6] = (short)f2bf(b.z); r[7] = (short)f2bf(b.w);
    return r;
}
__device__ __forceinline__ f32x4 mfma16(short8 a, short8 b, f32x4 c) {
    return __builtin_amdgcn_mfma_f32_16x16x32_bf16(a, b, c, 0, 0, 0);
}
// pack 2 f32 -> 1 dword of 2 bf16 (RNE); no builtin on gfx950
__device__ __forceinline__ u32 pk2(float a, float b) {
    u32 w;
    asm("v_cvt_pk_bf16_f32 %0, %1, %2" : "=v"(w) : "v"(a), "v"(b));
    return w;
}
__device__ __forceinline__ void gload_lds(const void* g, void* lds) {
    __builtin_amdgcn_global_load_lds(
        (const __attribute__((address_space(1))) void*)g,
        (__attribute__((address_space(3))) void*)lds, 16, 0, 0);
}

// ---------------------------------------------------------------- prep ----
__global__ __launch_bounds__(256, 1)
void prep_kernel(const float* __restrict__ k, const float* __restrict__ v,
                 const float* __restrict__ w0, const float* __restrict__ w1,
                 const float* __restrict__ w2, const float* __restrict__ w3,
                 char* __restrict__ ws)
{
    const int tid = (int)threadIdx.x;
    const int bid = (int)blockIdx.x;

    if (bid < 512) {
        // ---- V transpose tile: (b, jt) -> V^T [256 d][32 j] bf16, 80B row stride
        __shared__ float vs[32][257];
        const int b = bid >> 6, jt = bid & 63;
        const float* vb = v + ((size_t)b * S_ + (size_t)jt * 32) * D_;
        const int j = tid >> 3, d0 = (tid & 7) * 32;
        #pragma unroll
        for (int i = 0; i < 8; ++i) {
            float4 x = *(const float4*)(vb + (size_t)j * D_ + d0 + i * 4);
            vs[j][d0 + i * 4 + 0] = x.x; vs[j][d0 + i * 4 + 1] = x.y;
            vs[j][d0 + i * 4 + 2] = x.z; vs[j][d0 + i * 4 + 3] = x.w;
        }
        __syncthreads();
        char* ob = ws + VT_OFF + (size_t)b * VT_BATCH + (size_t)(jt >> 1) * VT_PERIOD
                   + (size_t)(jt & 1) * 20480 + (size_t)tid * 80;
        short8 o[4];
        #pragma unroll
        for (int jj = 0; jj < 32; ++jj) o[jj >> 3][jj & 7] = (short)f2bf(vs[jj][tid]);
        #pragma unroll
        for (int i = 0; i < 4; ++i) *(short8*)(ob + i * 16) = o[i];
    } else if (bid < 1024) {
        // ---- K tile -> swizzled bf16 LDS image: row r, byte = r*512 + ((cg*16) ^ ((r&7)<<4))
        const int t = bid - 512, b = t >> 6, jt = t & 63;
        const float* kb = k + ((size_t)b * S_ + (size_t)jt * 32) * D_;
        char* ob = ws + KSWZ_OFF + (size_t)(b * 64 + jt) * 16384;
        #pragma unroll
        for (int it = 0; it < 4; ++it) {
            int gi = tid + it * 256;
            int r = gi >> 5, cg = gi & 31;
            float4 x0 = *(const float4*)(kb + (size_t)r * D_ + cg * 8);
            float4 x1 = *(const float4*)(kb + (size_t)r * D_ + cg * 8 + 4);
            *(short8*)(ob + r * 512 + ((cg * 16) ^ ((r & 7) << 4))) = pack8(x0, x1);
        }
    } else {
        // ---- W slice (m, db): 16 rows x 256 cols -> swizzled bf16, chunk order (db*4+m)
        const int t = bid - 1024, m = t >> 4, db = t & 15;
        const float* wsrc = (m == 0 ? w0 : m == 1 ? w1 : m == 2 ? w2 : w3)
                            + (size_t)(db * 16) * D_;
        char* ob = ws + WBF_OFF + (size_t)(db * 4 + m) * 8192;
        #pragma unroll
        for (int it = 0; it < 2; ++it) {
            int gi = tid + it * 256;
            int r = gi >> 5, cg = gi & 31;
            float4 x0 = *(const float4*)(wsrc + (size_t)r * D_ + cg * 8);
            float4 x1 = *(const float4*)(wsrc + (size_t)r * D_ + cg * 8 + 4);
            *(short8*)(ob + r * 512 + ((cg * 16) ^ ((r & 7) << 4))) = pack8(x0, x1);
        }
    }
}

// ---------------------------------------------------------------- attn ----
// PV from repacked 16x16x32 P A-frag: B-frags = one b128 read per d-block from V^T.
#define PV_REG(pa_, accD, accS)                                                \
    {                                                                          \
        __builtin_amdgcn_s_setprio(1);                                         \
        accS = mfma16(pa_, onesb, accS);                                       \
        _Pragma("unroll")                                                      \
        for (int db = 0; db < 16; ++db) {                                      \
            short8 vb = *(const short8*)(vcur + (db * 16 + c) * 80 + g * 16);  \
            accD[db] = mfma16(pa_, vb, accD[db]);                              \
        }                                                                      \
        __builtin_amdgcn_s_setprio(0);                                         \
    }

__global__ __launch_bounds__(512, 2)
void attn_kernel(const float* __restrict__ q, const char* __restrict__ kswz,
                 const char* __restrict__ vt, const char* __restrict__ wbf,
                 const float* __restrict__ v,
                 const float* __restrict__ bo0, const float* __restrict__ bo1,
                 float* __restrict__ out)
{
    __shared__ char smem[147456];

    const int tid = (int)threadIdx.x;
    const int wv = tid >> 6, lane = tid & 63;
    const int h = wv >> 2, wl = wv & 3;
    const int g = lane >> 4, c = lane & 15;
    const int bid = (int)blockIdx.x;
    const int b = bid & 7, qi = bid >> 3;
    const int q0 = qi * QB;
    const int r0 = q0 + wl * 16;            // global q row base of this wave
    const int dt = r0 >> 5;                 // diagonal 32-j-block index

    const char* kbaseg = kswz + (size_t)b * (64 * 16384);
    const char* vbaseg = vt + (size_t)b * VT_BATCH;

    // bpermute gather indices (bytes): pair-group sources for the A-frag repack
    const int sA = (((g & 1) << 5) + c) << 2;   // lane (2*(g&1))*16 + c
    const int sB = sA + 64;                     // +16 lanes
    const bool lowh = (g < 2);

    // Q frags (pre-scaled). Used as the MFMA *B* operand in swapped QK^T.
    short8 qf[8];
    {
        const float* qp = q + ((size_t)b * S_ + (size_t)(r0 + c)) * D_;
        #pragma unroll
        for (int ks = 0; ks < 8; ++ks) {
            float4 a = *(const float4*)(qp + ks * 32 + g * 8);
            float4 d = *(const float4*)(qp + ks * 32 + g * 8 + 4);
            a.x *= QSCALE; a.y *= QSCALE; a.z *= QSCALE; a.w *= QSCALE;
            d.x *= QSCALE; d.y *= QSCALE; d.z *= QSCALE; d.w *= QSCALE;
            qf[ks] = pack8(a, d);
        }
    }

    short8 onesb;
    #pragma unroll
    for (int i = 0; i < 8; ++i) onesb[i] = (c == 0) ? (short)0x3F80 : (short)0;

    const f32x4 zero4 = {0.f, 0.f, 0.f, 0.f};
    f32x4 accF[16], accB[16], accSF = zero4, accSB = zero4;
    #pragma unroll
    for (int i = 0; i < 16; ++i) { accF[i] = zero4; accB[i] = zero4; }

    // stage one 64-row period: 32KB K (4 rounds) + 40KB V^T (5 rounds)
    #define STAGE(t, buf)                                                      \
        {                                                                      \
            const char* kg_ = kbaseg + (size_t)(t) * 32768;                    \
            const char* vg_ = vbaseg + (size_t)(t) * VT_PERIOD;                \
            _Pragma("unroll")                                                  \
            for (int i = 0; i < 4; ++i) {                                      \
                int off = i * 8192 + wv * 1024;                                \
                gload_lds(kg_ + off + lane * 16, smem + LDS_K + (buf) * 32768 + off); \
            }                                                                  \
            _Pragma("unroll")                                                  \
            for (int i = 0; i < 5; ++i) {                                      \
                int off = i * 8192 + wv * 1024;                                \
                gload_lds(vg_ + off + lane * 16, smem + LDS_V + (buf) * 40960 + off); \
            }                                                                  \
        }

    STAGE(0, 0);
    __syncthreads();

    const int swz = (c & 7) << 4;

    // repack u0,u1 (j 4g..4g+3) / v0,v1 (j 16+4g..+3) -> A-frag dwords j{8g..8g+7}
    #define REPACK(pa_, u0_, u1_, v0_, v1_)                                    \
        {                                                                      \
            u32 a0 = __builtin_amdgcn_ds_bpermute(sA, (int)(u0_));             \
            u32 b0 = __builtin_amdgcn_ds_bpermute(sA, (int)(v0_));             \
            u32 a1 = __builtin_amdgcn_ds_bpermute(sA, (int)(u1_));             \
            u32 b1 = __builtin_amdgcn_ds_bpermute(sA, (int)(v1_));             \
            u32 a2 = __builtin_amdgcn_ds_bpermute(sB, (int)(u0_));             \
            u32 b2 = __builtin_amdgcn_ds_bpermute(sB, (int)(v0_));             \
            u32 a3 = __builtin_amdgcn_ds_bpermute(sB, (int)(u1_));             \
            u32 b3 = __builtin_amdgcn_ds_bpermute(sB, (int)(v1_));             \
            union { u32 w[4]; short8 s; } r_;                                  \
            r_.w[0] = lowh ? a0 : b0;                                          \
            r_.w[1] = lowh ? a1 : b1;                                          \
            r_.w[2] = lowh ? a2 : b2;                                          \
            r_.w[3] = lowh ? a3 : b3;                                          \
            pa_ = r_.s;                                                        \
        }

    #pragma unroll 1
    for (int t = 0; t < NP; ++t) {
        const int cur = t & 1;
        if (t + 1 < NP) STAGE(t + 1, cur ^ 1);

        const int jw = 2 * t + h;           // this wave's 32-j block index
        const int j0 = jw * 32;
        const char* kcur = smem + LDS_K + cur * 32768 + h * 16384;
        const char* vcur = smem + LDS_V + cur * 40960 + h * 20480;

        // ---- swapped QK^T: scT[j][q]  (K rows as A, Q as B)
        f32x4 scT0 = zero4, scT1 = zero4;
        __builtin_amdgcn_s_setprio(1);
        #pragma unroll
        for (int ks = 0; ks < 8; ++ks) {
            int inner = (ks * 64 + g * 16) ^ swz;
            short8 kb0 = *(const short8*)(kcur + c * 512 + inner);
            short8 kb1 = *(const short8*)(kcur + (16 + c) * 512 + inner);
            scT0 = mfma16(kb0, qf[ks], scT0);
            scT1 = mfma16(kb1, qf[ks], scT1);
        }
        __builtin_amdgcn_s_setprio(0);

        // ---- softmax numerator in registers; repack to 16x16x32 A-frag; PV.
        // lane holds scT*[j = 4g + r][q = c]  (j relative to tile base)
        if (jw != dt) {
            u32 u0_ = pk2(exp2f(scT0[0]), exp2f(scT0[1]));
            u32 u1_ = pk2(exp2f(scT0[2]), exp2f(scT0[3]));
            u32 v0_ = pk2(exp2f(scT1[0]), exp2f(scT1[1]));
            u32 v1_ = pk2(exp2f(scT1[2]), exp2f(scT1[3]));
            short8 pa;
            REPACK(pa, u0_, u1_, v0_, v1_);
            if (jw < dt) {
                PV_REG(pa, accB, accSB);
            } else {
                PV_REG(pa, accF, accSF);
            }
        } else {
            const int qq = r0 + c;
            float m0[4], m1[4], n0[4], n1[4];
            #pragma unroll
            for (int r = 0; r < 4; ++r) {
                int jgl = j0 + 4 * g + r;
                int jgh = j0 + 16 + 4 * g + r;
                float e0 = exp2f(scT0[r]), e1 = exp2f(scT1[r]);
                m0[r] = (jgl <= qq) ? e0 : 0.0f;   // bw: j <= q
                m1[r] = (jgh <= qq) ? e1 : 0.0f;
                n0[r] = (jgl >= qq) ? e0 : 0.0f;   // fw: j >= q
                n1[r] = (jgh >= qq) ? e1 : 0.0f;
            }
            short8 pb, pf;
            REPACK(pb, pk2(m0[0], m0[1]), pk2(m0[2], m0[3]),
                       pk2(m1[0], m1[1]), pk2(m1[2], m1[3]));
            REPACK(pf, pk2(n0[0], n0[1]), pk2(n0[2], n0[3]),
                       pk2(n1[0], n1[1]), pk2(n1[2], n1[3]));
            PV_REG(pb, accB, accSB);
            PV_REG(pf, accF, accSF);
        }
        __syncthreads();
    }

    // ---- epilogue: merge halves, then fused gate ----
    float* sumsA = (float*)(smem + LDS_SUM);        // sF partial from half1 (64)
    float* sumsB = (float*)(smem + LDS_SUM + 256);  // sB partial from half0 (64)

    // P0: exchange partials (half1 acc-F -> [0,64K), half0 acc-B -> [64K,128K))
    if (h == 1) {
        float* dst = (float*)smem + wl * 4096;
        #pragma unroll
        for (int db = 0; db < 16; ++db)
            #pragma unroll
            for (int r = 0; r < 4; ++r)
                dst[(g * 4 + r) * 256 + db * 16 + c] = accF[db][r];
        if (c == 0) {
            #pragma unroll
            for (int r = 0; r < 4; ++r) sumsA[wl * 16 + g * 4 + r] = accSF[r];
        }
    } else {
        float* dst = (float*)(smem + LDS_V) + wl * 4096;
        #pragma unroll
        for (int db = 0; db < 16; ++db)
            #pragma unroll
            for (int r = 0; r < 4; ++r)
                dst[(g * 4 + r) * 256 + db * 16 + c] = accB[db][r];
        if (c == 0) {
            #pragma unroll
            for (int r = 0; r < 4; ++r) sumsB[wl * 16 + g * 4 + r] = accSB[r];
        }
    }
    __syncthreads();

    // P1: merge + normalize. half0 owns fw rows, half1 owns bw rows.
    f32x4 merged[16];
    if (h == 0) {
        const float* src = (const float*)smem + wl * 4096;
        float rs[4];
        #pragma unroll
        for (int r = 0; r < 4; ++r) {
            float so = __shfl(accSF[r], lane & 48);
            rs[r] = 1.0f / (so + sumsA[wl * 16 + g * 4 + r]);
        }
        #pragma unroll
        for (int db = 0; db < 16; ++db)
            #pragma unroll
            for (int r = 0; r < 4; ++r)
                merged[db][r] = (accF[db][r] + src[(g * 4 + r) * 256 + db * 16 + c]) * rs[r];
    } else {
        const float* src = (const float*)(smem + LDS_V) + wl * 4096;
        float rs[4];
        #pragma unroll
        for (int r = 0; r < 4; ++r) {
            float so = __shfl(accSB[r], lane & 48);
            rs[r] = 1.0f / (so + sumsB[wl * 16 + g * 4 + r]);
        }
        #pragma unroll
        for (int db = 0; db < 16; ++db)
            #pragma unroll
            for (int r = 0; r < 4; ++r)
                merged[db][r] = (accB[db][r] + src[(g * 4 + r) * 256 + db * 16 + c]) * rs[r];
    }
    __syncthreads();

    // P2: write att_v bf16 swizzled image (h0: fw @[0,32K), h1: bw @[32K,64K)) + stage W chunk 0
    {
        char* imgb = smem + h * 32768;
        #pragma unroll
        for (int db = 0; db < 16; ++db)
            #pragma unroll
            for (int r = 0; r < 4; ++r) {
                int lr = wl * 16 + g * 4 + r;
                int cb = (db * 16 + c) * 2;
                *(u16*)(imgb + lr * 512 + (cb ^ ((lr & 7) << 4))) = f2bf(merged[db][r]);
            }
    }
    #define WSTAGE(db, buf)                                                    \
        {                                                                      \
            const char* gsrc = wbf + (size_t)(db) * 32768;                     \
            _Pragma("unroll")                                                  \
            for (int i = 0; i < 4; ++i) {                                      \
                int off = i * 8192 + wv * 1024;                                \
                gload_lds(gsrc + off + lane * 16,                              \
                          smem + LDS_V + (buf) * 32768 + off);                 \
            }                                                                  \
        }
    WSTAGE(0, 0);
    __syncthreads();

    // P3: A-frags for own direction (att image) and v (global)
    short8 af[8], vf[8];
    {
        const char* imgb = smem + h * 32768;
        int lr = wl * 16 + c;
        #pragma unroll
        for (int ks = 0; ks < 8; ++ks) {
            int inner = (ks * 64 + g * 16) ^ swz;
            af[ks] = *(const short8*)(imgb + lr * 512 + inner);
        }
        const float* vp = v + ((size_t)b * S_ + (size_t)(r0 + c)) * D_;
        #pragma unroll
        for (int ks = 0; ks < 8; ++ks) {
            float4 a = *(const float4*)(vp + ks * 32 + g * 8);
            float4 d = *(const float4*)(vp + ks * 32 + g * 8 + 4);
            vf[ks] = pack8(a, d);
        }
    }

    // db loop: gate GEMM (own direction) + blend + store
    const float* bias = (h == 0) ? bo0 : bo1;
    const float* vrow = v + ((size_t)b * S_ + (size_t)r0) * D_;
    float* ob = out + ((size_t)b * S_ + (size_t)r0) * 512 + h * 256;
    #pragma unroll
    for (int db = 0; db < 16; ++db) {
        const int cu2 = db & 1;
        if (db + 1 < 16) WSTAGE(db + 1, cu2 ^ 1);

        float bb = bias[db * 16 + c];
        f32x4 a = {bb, bb, bb, bb};
        const char* wc = smem + LDS_V + cu2 * 32768 + h * 16384;
        __builtin_amdgcn_s_setprio(1);
        #pragma unroll
        for (int ks = 0; ks < 8; ++ks) {
            int inner = (ks * 64 + g * 16) ^ swz;
            short8 wi = *(const short8*)(wc + c * 512 + inner);
            short8 wo = *(const short8*)(wc + 8192 + c * 512 + inner);
            a = mfma16(vf[ks], wi, a);
            a = mfma16(af[ks], wo, a);
        }
        __builtin_amdgcn_s_setprio(0);

        #pragma unroll
        for (int r = 0; r < 4; ++r) {
            int row = g * 4 + r;
            float vv = vrow[(size_t)row * D_ + db * 16 + c];
            float gate = 1.0f / (1.0f + exp2f(-a[r] * LOG2E));
            float m = merged[db][r];
            ob[(size_t)row * 512 + db * 16 + c] = gate * m + (1.0f - gate) * vv;
        }
        __syncthreads();
    }
}

extern "C" void kernel_launch(void* const* d_in, const int* in_sizes, int n_in,
                              void* d_out, int out_size, void* d_ws, size_t ws_size,
                              hipStream_t stream)
{
    const float* q   = (const float*)d_in[0];
    const float* k   = (const float*)d_in[1];
    const float* v   = (const float*)d_in[2];
    const float* Wi0 = (const float*)d_in[3];
    const float* Wi1 = (const float*)d_in[4];
    const float* Wo0 = (const float*)d_in[5];
    const float* Wo1 = (const float*)d_in[6];
    const float* bo0 = (const float*)d_in[7];
    const float* bo1 = (const float*)d_in[8];
    float* out = (float*)d_out;
    char* ws = (char*)d_ws;
    (void)in_sizes; (void)n_in; (void)ws_size; (void)out_size;

    // prep: K-swz [0,8MB), V^T 80B-stride [8MB,18MB), W-bf16 chunks [18MB,+512KB)
    prep_kernel<<<dim3(1088), dim3(256), 0, stream>>>(k, v, Wi0, Wo0, Wi1, Wo1, ws);
    attn_kernel<<<dim3(256), dim3(512), 0, stream>>>(q, ws + KSWZ_OFF, ws + VT_OFF,
                                                     ws + WBF_OFF, v, bo0, bo1, out);
}